// Round 7
// baseline (311.664 us; speedup 1.0000x reference)
//
#include <hip/hip_runtime.h>
#include <hip/hip_bf16.h>
#include <cstdint>

typedef unsigned short u16;
typedef unsigned int   u32;

typedef __attribute__((ext_vector_type(8))) short short8;   // 8 x bf16 (4 VGPRs)
typedef __attribute__((ext_vector_type(4))) float f32x4;    // MFMA accumulator

__device__ __forceinline__ float b2f(u16 v) { return __uint_as_float(((u32)v) << 16); }
__device__ __forceinline__ u16 f2b(float f) {
    u32 u = __float_as_uint(f);
    u += 0x7FFFu + ((u >> 16) & 1u);   // round-to-nearest-even
    return (u16)(u >> 16);
}

#define G2L16(gp, lp) __builtin_amdgcn_global_load_lds(                       \
    (const __attribute__((address_space(1))) void*)(gp),                      \
    (__attribute__((address_space(3))) void*)(lp), 16, 0, 0)

// ---------------------------------------------------------------------------
// Mega-prologue (ALL work before gemm1, one dispatch):
//   blocks [0,1024)      : W1 (1024x1024 f32) -> W1t (bf16, transposed)
//   blocks [1024,2048)   : W2 -> W2t
//   blocks [2048,6144)   : Wg (2048x2048) -> Wgt
//   blocks [6144,14336)  : cast iQ f32 -> iQb bf16
//   blocks [14336,14464) : causal cumulative mean of iV -> avg (bf16),
//                          one block per (batch, 32-wide d-strip); the chunk
//                          prefix is done fully in-block via LDS.
// ---------------------------------------------------------------------------
__device__ __forceinline__ void transpose_body(const float* __restrict__ in,
                                               u16* __restrict__ out,
                                               int R, int C, int lb, int tilesX,
                                               float (*tile)[33]) {
    const int bx = (lb % tilesX) * 32;
    const int by = (lb / tilesX) * 32;
    const int tx = threadIdx.x & 31, ty = threadIdx.x >> 5;   // 32 x 8
    #pragma unroll
    for (int i = 0; i < 32; i += 8)
        tile[ty + i][tx] = in[(size_t)(by + ty + i) * C + (bx + tx)];
    __syncthreads();
    #pragma unroll
    for (int i = 0; i < 32; i += 8)
        out[(size_t)(bx + ty + i) * R + (by + tx)] = f2b(tile[tx][ty + i]);
}

__global__ void prologue_kernel(const float* __restrict__ W1, u16* __restrict__ W1t,
                                const float* __restrict__ W2, u16* __restrict__ W2t,
                                const float* __restrict__ Wg, u16* __restrict__ Wgt,
                                const float* __restrict__ iQ, u16* __restrict__ iQb,
                                const float* __restrict__ iV, u16* __restrict__ avg) {
    __shared__ float tile[32][33];
    const int bid = blockIdx.x;
    const int tid = threadIdx.x;
    if (bid < 1024) {
        transpose_body(W1, W1t, 1024, 1024, bid, 32, tile);
    } else if (bid < 2048) {
        transpose_body(W2, W2t, 1024, 1024, bid - 1024, 32, tile);
    } else if (bid < 6144) {
        transpose_body(Wg, Wgt, 2048, 2048, bid - 2048, 64, tile);
    } else if (bid < 14336) {
        const size_t i = ((size_t)(bid - 6144) * 256 + tid) * 4;
        const float4 v = *(const float4*)(iQ + i);
        ushort4 o;
        o.x = f2b(v.x); o.y = f2b(v.y); o.z = f2b(v.z); o.w = f2b(v.w);
        *(ushort4*)(iQb + i) = o;
    } else {
        // cumavg: block = (batch b, 32-float d-strip). 256 thr = 32 d x 8 groups
        // of 256 rows. Pass 1: per-group sums. LDS prefix. Pass 2: rescan+emit.
        float (*psum)[32] = (float (*)[32])tile;     // 8 x 32 floats, reuse LDS
        const int idx   = bid - 14336;               // 0..127
        const int b     = idx >> 5;
        const int strip = idx & 31;
        const int d     = tid & 31;
        const int g     = tid >> 5;                  // row group 0..7
        const int col   = strip * 32 + d;
        const float* base = iV + ((size_t)(b * 2048 + g * 256)) * 1024 + col;
        float s = 0.f;
        #pragma unroll 8
        for (int i = 0; i < 256; ++i) s += base[(size_t)i * 1024];
        psum[g][d] = s;
        __syncthreads();
        float acc = 0.f;
        for (int gg = 0; gg < g; ++gg) acc += psum[gg][d];
        u16* dst = avg + ((size_t)(b * 2048 + g * 256)) * 1024 + col;
        const int s0 = g * 256;
        #pragma unroll 8
        for (int i = 0; i < 256; ++i) {
            acc += base[(size_t)i * 1024];
            dst[(size_t)i * 1024] = f2b(acc / (float)(s0 + i + 1));
        }
    }
}

// ---------------------------------------------------------------------------
// MFMA GEMM, BK=64, 8-slot XOR-swizzled LDS (round-4 config — measured good).
// 128x128 block, 4 waves, 4x4 16x16x32 frags/wave.  EPI: 0 = relu, 1 = none.
// ---------------------------------------------------------------------------
template <int EPI>
__global__ __launch_bounds__(256, 2)
void gemm_kernel(const u16* __restrict__ A, const u16* __restrict__ Bt,
                 const float* __restrict__ bias, u16* __restrict__ C,
                 int M, int N, int K) {
    __shared__ u16 As[128 * 64];
    __shared__ u16 Bs[128 * 64];

    const int tid  = threadIdx.x;
    const int m0   = blockIdx.x * 128;
    const int n0   = blockIdx.y * 128;
    const int wave = tid >> 6, lane = tid & 63;
    const int wm   = (wave & 1) << 6;
    const int wn   = (wave >> 1) << 6;
    const int quad = lane >> 4, l16 = lane & 15;

    f32x4 acc[4][4];
    #pragma unroll
    for (int i = 0; i < 4; ++i)
        #pragma unroll
        for (int j = 0; j < 4; ++j) acc[i][j] = (f32x4){0.f, 0.f, 0.f, 0.f};

    int oo[4], rr[4], qq[4];
    #pragma unroll
    for (int j = 0; j < 4; ++j) {
        oo[j] = tid * 16 + j * 4096;
        rr[j] = oo[j] >> 7;
        qq[j] = ((oo[j] >> 4) & 7) ^ (rr[j] & 7);
    }

    const int ktiles = K >> 6;
    for (int kt = 0; kt < ktiles; ++kt) {
        const int kb = kt << 6;
        #pragma unroll
        for (int j = 0; j < 4; ++j) {
            G2L16((const char*)A  + ((size_t)(m0 + rr[j]) * K + kb) * 2 + qq[j] * 16,
                  (char*)As + oo[j]);
            G2L16((const char*)Bt + ((size_t)(n0 + rr[j]) * K + kb) * 2 + qq[j] * 16,
                  (char*)Bs + oo[j]);
        }
        __syncthreads();

        #pragma unroll
        for (int h = 0; h < 2; ++h) {
            short8 af[4], bf[4];
            #pragma unroll
            for (int mi = 0; mi < 4; ++mi) {
                const int R = wm + mi * 16 + l16;
                af[mi] = *(const short8*)(As + R * 64 + ((((h << 2) | quad) ^ (R & 7)) << 3));
            }
            #pragma unroll
            for (int ni = 0; ni < 4; ++ni) {
                const int R = wn + ni * 16 + l16;
                bf[ni] = *(const short8*)(Bs + R * 64 + ((((h << 2) | quad) ^ (R & 7)) << 3));
            }
            #pragma unroll
            for (int mi = 0; mi < 4; ++mi)
                #pragma unroll
                for (int ni = 0; ni < 4; ++ni)
                    acc[mi][ni] = __builtin_amdgcn_mfma_f32_16x16x32_bf16(
                        af[mi], bf[ni], acc[mi][ni], 0, 0, 0);
        }
        __syncthreads();
    }

    #pragma unroll
    for (int ni = 0; ni < 4; ++ni) {
        const int col = n0 + wn + ni * 16 + l16;
        const float bv = bias[col];
        #pragma unroll
        for (int mi = 0; mi < 4; ++mi) {
            const int row0 = m0 + wm + mi * 16 + quad * 4;
            #pragma unroll
            for (int r = 0; r < 4; ++r) {
                float v = acc[mi][ni][r] + bv;
                if (EPI == 0) v = fmaxf(v, 0.f);
                C[(size_t)(row0 + r) * N + col] = f2b(v);
            }
        }
    }
}

// ---------------------------------------------------------------------------
// Fused GEMM3 + sigmoid + gate.  BK=32, dual page in-register, 2-row-group
// XOR swizzle (conflict-free, measured 0 conflicts round 6).
// ---------------------------------------------------------------------------
__global__ __launch_bounds__(256, 2)
void gemm_gate_kernel(const u16* __restrict__ iQb, const u16* __restrict__ ffn,
                      const u16* __restrict__ Wgt, const float* __restrict__ bg,
                      const float* __restrict__ iQ, float* __restrict__ out,
                      int M, int D2 /*2048*/) {
    __shared__ u16 As [128 * 32];
    __shared__ u16 Bs0[128 * 32];
    __shared__ u16 Bs1[128 * 32];

    const int tid  = threadIdx.x;
    const int m0   = blockIdx.x * 128;
    const int n0   = blockIdx.y * 128;          // out-col tile, n0 < 1024
    const int wave = tid >> 6, lane = tid & 63;
    const int wm   = (wave & 1) << 6;
    const int wn   = (wave >> 1) << 6;
    const int quad = lane >> 4, l16 = lane & 15;
    const int D = D2 >> 1;                      // 1024

    f32x4 acc[2][4][4];
    #pragma unroll
    for (int p = 0; p < 2; ++p)
        #pragma unroll
        for (int i = 0; i < 4; ++i)
            #pragma unroll
            for (int j = 0; j < 4; ++j) acc[p][i][j] = (f32x4){0.f, 0.f, 0.f, 0.f};

    // staging: 2 issues of 4KB per buffer; 2-row-group swizzle
    int oo[2], grow[2], gcol[2];
    #pragma unroll
    for (int j = 0; j < 2; ++j) {
        oo[j] = tid * 16 + j * 4096;
        const int rp = oo[j] >> 7;              // row-group 0..63
        const int s  = (oo[j] >> 4) & 7;        // slot in group
        const int ch = s ^ (rp & 7);            // global chunk 0..7
        grow[j] = rp * 2 + (ch >> 2);           // global row 0..127
        gcol[j] = (ch & 3) * 16;                // byte offset in 64B k-window
    }

    const int ktiles = D2 >> 5;                 // 64
    for (int kt = 0; kt < ktiles; ++kt) {
        const int kb = kt << 5;
        const char* Ab = (const char*)((kb < D) ? (iQb + kb) : (ffn + (kb - D)));
        const char* B0 = (const char*)(Wgt + (size_t)n0 * D2 + kb);
        const char* B1 = (const char*)(Wgt + (size_t)(n0 + D) * D2 + kb);
        #pragma unroll
        for (int j = 0; j < 2; ++j) {
            G2L16(Ab + (size_t)(m0 + grow[j]) * D * 2 + gcol[j], (char*)As  + oo[j]);
            G2L16(B0 + (size_t)grow[j] * D2 * 2 + gcol[j],       (char*)Bs0 + oo[j]);
            G2L16(B1 + (size_t)grow[j] * D2 * 2 + gcol[j],       (char*)Bs1 + oo[j]);
        }
        __syncthreads();

        short8 af[4], bf0[4], bf1[4];
        #pragma unroll
        for (int mi = 0; mi < 4; ++mi) {
            const int R = wm + mi * 16 + l16;
            const int so = (R >> 1) * 64 +
                           (((((R & 1) << 2) | quad) ^ ((R >> 1) & 7)) << 3);
            af[mi] = *(const short8*)(As + so);
        }
        #pragma unroll
        for (int ni = 0; ni < 4; ++ni) {
            const int R = wn + ni * 16 + l16;
            const int so = (R >> 1) * 64 +
                           (((((R & 1) << 2) | quad) ^ ((R >> 1) & 7)) << 3);
            bf0[ni] = *(const short8*)(Bs0 + so);
            bf1[ni] = *(const short8*)(Bs1 + so);
        }
        #pragma unroll
        for (int mi = 0; mi < 4; ++mi)
            #pragma unroll
            for (int ni = 0; ni < 4; ++ni) {
                acc[0][mi][ni] = __builtin_amdgcn_mfma_f32_16x16x32_bf16(
                    af[mi], bf0[ni], acc[0][mi][ni], 0, 0, 0);
                acc[1][mi][ni] = __builtin_amdgcn_mfma_f32_16x16x32_bf16(
                    af[mi], bf1[ni], acc[1][mi][ni], 0, 0, 0);
            }
        __syncthreads();
    }

    #pragma unroll
    for (int ni = 0; ni < 4; ++ni) {
        const int col = n0 + wn + ni * 16 + l16;
        const float bgi = bg[col];
        const float bgf = bg[col + D];
        #pragma unroll
        for (int mi = 0; mi < 4; ++mi) {
            const int row0 = m0 + wm + mi * 16 + quad * 4;
            #pragma unroll
            for (int r = 0; r < 4; ++r) {
                const size_t idx = (size_t)(row0 + r) * D + col;
                const float gi = 1.0f / (1.0f + __expf(-(acc[0][mi][ni][r] + bgi)));
                const float gf = 1.0f / (1.0f + __expf(-(acc[1][mi][ni][r] + bgf)));
                out[idx] = gi * iQ[idx] + gf * b2f(ffn[idx]);
            }
        }
    }
}

// ---------------------------------------------------------------------------
extern "C" void kernel_launch(void* const* d_in, const int* in_sizes, int n_in,
                              void* d_out, int out_size, void* d_ws, size_t ws_size,
                              hipStream_t stream) {
    const int B = 4, S = 2048, D = 1024, D2 = 2048;
    const int M = B * S;  // 8192

    const float* iQ = (const float*)d_in[0];
    const float* iV = (const float*)d_in[1];
    const float* W1 = (const float*)d_in[2];
    const float* b1 = (const float*)d_in[3];
    const float* W2 = (const float*)d_in[4];
    const float* b2 = (const float*)d_in[5];
    const float* Wg = (const float*)d_in[6];
    const float* bg = (const float*)d_in[7];
    float* out = (float*)d_out;

    // workspace (60 MB):
    u16* regA = (u16*)d_ws;                    // avg -> (after gemm1) ffn (16 MB)
    u16* regB = regA + (size_t)M * D;          // h                       (16 MB)
    u16* iQb  = regB + (size_t)M * D;          // iQ bf16                 (16 MB)
    u16* W1t  = iQb  + (size_t)M * D;          //                         ( 2 MB)
    u16* W2t  = W1t  + (size_t)D * D;          //                         ( 2 MB)
    u16* Wgt  = W2t  + (size_t)D * D;          //                         ( 8 MB)

    u16* avg = regA;
    u16* ffn = regA;
    u16* h   = regB;

    // 1. mega-prologue: transposes + cast + full causal cumulative mean
    prologue_kernel<<<14464, 256, 0, stream>>>(W1, W1t, W2, W2t, Wg, Wgt,
                                               iQ, iQb, iV, avg);
    // 2. h = relu(avg @ W1 + b1)
    gemm_kernel<0><<<dim3(M / 128, D / 128), 256, 0, stream>>>(avg, W1t, b1, h, M, D, D);
    // 3. ffn = h @ W2 + b2   (overlays avg)
    gemm_kernel<1><<<dim3(M / 128, D / 128), 256, 0, stream>>>(h, W2t, b2, ffn, M, D, D);
    // 4. fused gate GEMM + epilogue
    gemm_gate_kernel<<<dim3(M / 128, D / 128), 256, 0, stream>>>(
        iQb, ffn, Wgt, bg, iQ, out, M, D2);
}